// Round 1
// baseline (411.126 us; speedup 1.0000x reference)
//
#include <hip/hip_runtime.h>
#include <hip/hip_bf16.h>

typedef short s16x8 __attribute__((ext_vector_type(8)));
typedef float f32x4 __attribute__((ext_vector_type(4)));
typedef unsigned short u16;

#define SEQ  1370
#define CH   1024
#define NH   16
#define HD   64
#define BN   5480      // 4*1370
#define MPAD 5504      // 86*64
#define NPAD 1408      // 22*64
#define NKT  43        // ceil(1370/32)

__device__ __forceinline__ u16 f2bf(float f){
  union { float f; unsigned u; } v; v.f = f;
  unsigned u = v.u;
  return (u16)((u + 0x7FFFu + ((u >> 16) & 1u)) >> 16);   // RNE
}

// ---- casts ----
__global__ __launch_bounds__(256) void k_cast_tokens(const float* __restrict__ in, u16* __restrict__ out){
  int i = blockIdx.x * 256 + threadIdx.x;
  if(i >= MPAD*CH) return;
  int row = i >> 10;
  out[i] = (row < BN) ? f2bf(in[i]) : (u16)0;   // zero-pad M tail
}

__global__ __launch_bounds__(256) void k_cast(const float* __restrict__ in, u16* __restrict__ out, int n){
  int i = blockIdx.x * 256 + threadIdx.x;
  if(i < n) out[i] = f2bf(in[i]);
}

// ---- NT GEMM: C[m][n] = sum_k A[m][k]*B[n][k] (+bias), 64x64 tile, 4 waves ----
// MODE 0: QKV epilogue (scatter q*scale / k / v into [bh][NPAD][64] bf16)
// MODE 1: proj epilogue (fp32 out + bias)
template<int MODE>
__global__ __launch_bounds__(256) void k_gemm(
    const u16* __restrict__ A, const u16* __restrict__ Bw, const float* __restrict__ bias,
    u16* __restrict__ q, u16* __restrict__ kk, u16* __restrict__ vv, float* __restrict__ out)
{
  __shared__ u16 As[64][40];   // +8 pad: rows stride 80B -> 16B-aligned, banks spread
  __shared__ u16 Bs[64][40];
  const int m0 = blockIdx.x * 64;
  const int n0 = blockIdx.y * 64;
  const int t = threadIdx.x;
  const int lane = t & 63;
  const int w = t >> 6;
  const int wm = w >> 1, wn = w & 1;        // 2x2 wave grid, 32x32 per wave
  const int g = lane >> 4, lr = lane & 15;
  const int ldrow = t >> 2, ldc = (t & 3) * 8;

  f32x4 z = {0.f,0.f,0.f,0.f};
  f32x4 acc[2][2] = {{z,z},{z,z}};

  for(int k0 = 0; k0 < 1024; k0 += 32){
    s16x8 av = *reinterpret_cast<const s16x8*>(A  + (size_t)(m0 + ldrow) * 1024 + k0 + ldc);
    s16x8 bv = *reinterpret_cast<const s16x8*>(Bw + (size_t)(n0 + ldrow) * 1024 + k0 + ldc);
    __syncthreads();
    *reinterpret_cast<s16x8*>(&As[ldrow][ldc]) = av;
    *reinterpret_cast<s16x8*>(&Bs[ldrow][ldc]) = bv;
    __syncthreads();
    s16x8 af0 = *reinterpret_cast<const s16x8*>(&As[wm*32      + lr][g*8]);
    s16x8 af1 = *reinterpret_cast<const s16x8*>(&As[wm*32 + 16 + lr][g*8]);
    s16x8 bf0 = *reinterpret_cast<const s16x8*>(&Bs[wn*32      + lr][g*8]);
    s16x8 bf1 = *reinterpret_cast<const s16x8*>(&Bs[wn*32 + 16 + lr][g*8]);
    acc[0][0] = __builtin_amdgcn_mfma_f32_16x16x32_bf16(af0, bf0, acc[0][0], 0,0,0);
    acc[0][1] = __builtin_amdgcn_mfma_f32_16x16x32_bf16(af0, bf1, acc[0][1], 0,0,0);
    acc[1][0] = __builtin_amdgcn_mfma_f32_16x16x32_bf16(af1, bf0, acc[1][0], 0,0,0);
    acc[1][1] = __builtin_amdgcn_mfma_f32_16x16x32_bf16(af1, bf1, acc[1][1], 0,0,0);
  }

  for(int mi = 0; mi < 2; mi++){
    for(int ni = 0; ni < 2; ni++){
      int col = n0 + wn*32 + ni*16 + lr;
      float bb = bias[col];
      for(int r = 0; r < 4; r++){
        int row = m0 + wm*32 + mi*16 + g*4 + r;   // C/D: col=lane&15, row=(lane>>4)*4+reg
        if(row >= BN) continue;
        float v = acc[mi][ni][r] + bb;
        if constexpr (MODE == 0){
          int b = row / SEQ, n = row - b*SEQ;
          int tt = col >> 10, h = (col >> 6) & 15, cc = col & 63;
          size_t bh = (size_t)(b*NH + h);
          if(tt == 0)      q [(bh*NPAD + n)*HD + cc] = f2bf(v * 0.125f);  // fold scale (pow2: exact)
          else if(tt == 1) kk[(bh*NPAD + n)*HD + cc] = f2bf(v);
          else             vv[(bh*NPAD + n)*HD + cc] = f2bf(v);
        } else {
          out[(size_t)row * CH + col] = v;
        }
      }
    }
  }
}

// ---- V[bh][n][cc] -> Vt[bh][cc][n], zero-fills n in [SEQ,NPAD) ----
__global__ __launch_bounds__(256) void k_transpose_v(const u16* __restrict__ V, u16* __restrict__ Vt){
  __shared__ u16 Ts[64][80];
  const int bh = blockIdx.x, nt = blockIdx.y;
  const int n0 = nt * 64;
  const int t = threadIdx.x;
  const int row = t >> 3;         // 0..31
  const int c8  = (t & 7) * 8;
  const u16* vb = V + (size_t)bh * NPAD * HD;
  for(int i = 0; i < 2; i++){
    int r = row + i*32;
    int n = n0 + r;
    s16x8 val = {0,0,0,0,0,0,0,0};
    if(n < SEQ) val = *reinterpret_cast<const s16x8*>(vb + (size_t)n*HD + c8);
    *reinterpret_cast<s16x8*>(&Ts[r][c8]) = val;
  }
  __syncthreads();
  u16* vtb = Vt + (size_t)bh * HD * NPAD;
  for(int i = 0; i < 2; i++){
    int cc = row + i*32;
    s16x8 o;
    for(int j = 0; j < 8; j++) o[j] = Ts[c8 + j][cc];
    *reinterpret_cast<s16x8*>(vtb + (size_t)cc*NPAD + n0 + c8) = o;
  }
}

// ---- flash attention: block = (bh, qtile of 64 rows), 4 waves x 16 q-rows ----
__global__ __launch_bounds__(256) void k_attn(
    const u16* __restrict__ Q, const u16* __restrict__ K,
    const u16* __restrict__ Vt, u16* __restrict__ O)
{
  __shared__ u16 plds[4][16][40];   // per-wave P transpose buffer
  const int bh = blockIdx.x;
  const int qt = blockIdx.y;
  const int t = threadIdx.x, lane = t & 63, w = t >> 6;
  const int g = lane >> 4, lr = lane & 15;
  const int n0 = qt * 64 + w * 16;

  const u16* qbase = Q + ((size_t)bh * NPAD + n0) * HD;
  s16x8 qf0 = *reinterpret_cast<const s16x8*>(qbase + lr*HD + g*8);        // Q rows, c 0..31
  s16x8 qf1 = *reinterpret_cast<const s16x8*>(qbase + lr*HD + 32 + g*8);   // c 32..63

  const u16* kb = K  + (size_t)bh * NPAD * HD;
  const u16* vb = Vt + (size_t)bh * HD * NPAD;

  f32x4 z = {0.f,0.f,0.f,0.f};
  f32x4 accO[4] = {z,z,z,z};                 // cc tiles 0..3 (16 each)
  float m_run[4] = {-1e30f,-1e30f,-1e30f,-1e30f};
  float l_run[4] = {0.f,0.f,0.f,0.f};

  for(int kt = 0; kt < NKT; kt++){
    const int kj0 = kt * 32;
    f32x4 s0 = z, s1 = z;
    {
      const u16* kr0 = kb + (size_t)(kj0 + lr) * HD + g*8;
      const u16* kr1 = kb + (size_t)(kj0 + 16 + lr) * HD + g*8;
      s16x8 ka = *reinterpret_cast<const s16x8*>(kr0);
      s16x8 kc = *reinterpret_cast<const s16x8*>(kr0 + 32);
      s16x8 ke = *reinterpret_cast<const s16x8*>(kr1);
      s16x8 kd = *reinterpret_cast<const s16x8*>(kr1 + 32);
      s0 = __builtin_amdgcn_mfma_f32_16x16x32_bf16(qf0, ka, s0, 0,0,0);
      s0 = __builtin_amdgcn_mfma_f32_16x16x32_bf16(qf1, kc, s0, 0,0,0);
      s1 = __builtin_amdgcn_mfma_f32_16x16x32_bf16(qf0, ke, s1, 0,0,0);
      s1 = __builtin_amdgcn_mfma_f32_16x16x32_bf16(qf1, kd, s1, 0,0,0);
    }
    const bool ok0 = (kj0 + lr) < SEQ;        // mask invalid kj columns
    const bool ok1 = (kj0 + 16 + lr) < SEQ;
    float p0[4], p1[4], alpha[4];
    for(int r = 0; r < 4; r++){
      float a = ok0 ? s0[r] : -1e30f;
      float b = ok1 ? s1[r] : -1e30f;
      float mx = fmaxf(a, b);
      mx = fmaxf(mx, __shfl_xor(mx, 1));
      mx = fmaxf(mx, __shfl_xor(mx, 2));
      mx = fmaxf(mx, __shfl_xor(mx, 4));
      mx = fmaxf(mx, __shfl_xor(mx, 8));      // row max over 16 lanes
      float mnew = fmaxf(m_run[r], mx);
      alpha[r] = __expf(m_run[r] - mnew);
      m_run[r] = mnew;
      float e0 = __expf(a - mnew);
      float e1 = __expf(b - mnew);
      p0[r] = e0; p1[r] = e1;
      float sm = e0 + e1;
      sm += __shfl_xor(sm, 1);
      sm += __shfl_xor(sm, 2);
      sm += __shfl_xor(sm, 4);
      sm += __shfl_xor(sm, 8);
      l_run[r] = l_run[r] * alpha[r] + sm;
    }
    for(int c = 0; c < 4; c++)
      for(int r = 0; r < 4; r++)
        accO[c][r] *= alpha[r];
    // P (D-layout: col=lr,row=g*4+r) -> LDS [qi][kj] -> A-frag (row=lr, k contiguous)
    for(int r = 0; r < 4; r++){
      plds[w][g*4 + r][lr]      = f2bf(p0[r]);
      plds[w][g*4 + r][16 + lr] = f2bf(p1[r]);
    }
    s16x8 pf = *reinterpret_cast<const s16x8*>(&plds[w][lr][g*8]);
    for(int c = 0; c < 4; c++){
      const u16* vr = vb + (size_t)(c*16 + lr) * NPAD + kj0 + g*8;
      s16x8 vf = *reinterpret_cast<const s16x8*>(vr);
      accO[c] = __builtin_amdgcn_mfma_f32_16x16x32_bf16(pf, vf, accO[c], 0,0,0);
    }
  }

  const int b = bh >> 4, h = bh & 15;
  for(int r = 0; r < 4; r++){
    int n = n0 + g*4 + r;
    if(n >= SEQ) continue;
    float inv = 1.0f / l_run[r];
    u16* orow = O + ((size_t)(b*SEQ + n)) * CH + h*HD;
    for(int c = 0; c < 4; c++)
      orow[c*16 + lr] = f2bf(accO[c][r] * inv);
  }
}

extern "C" void kernel_launch(void* const* d_in, const int* in_sizes, int n_in,
                              void* d_out, int out_size, void* d_ws, size_t ws_size,
                              hipStream_t stream)
{
  const float* tokens = (const float*)d_in[0];
  const float* qkv_w  = (const float*)d_in[1];
  const float* qkv_b  = (const float*)d_in[2];
  const float* proj_w = (const float*)d_in[3];
  const float* proj_b = (const float*)d_in[4];
  float* out = (float*)d_out;

  char* ws = (char*)d_ws;
  u16* Xbf   = (u16*)(ws);              // MPAD*1024          = 11,272,192 B
  u16* Wqkv  = (u16*)(ws + 11272192);   // 3072*1024*2        =  6,291,456
  u16* Wproj = (u16*)(ws + 17563648);   // 1024*1024*2        =  2,097,152
  u16* Qb    = (u16*)(ws + 19660800);   // 64*1408*64*2       = 11,534,336
  u16* Kb    = (u16*)(ws + 31195136);
  u16* Vb    = (u16*)(ws + 42729472);
  u16* Vt    = (u16*)(ws + 54263808);
  u16* AttO  = (u16*)(ws + 65798144);   // MPAD*1024*2 ; end ~77 MB

  k_cast_tokens<<<dim3((MPAD*CH)/256), 256, 0, stream>>>(tokens, Xbf);
  k_cast<<<dim3((3*CH*CH)/256), 256, 0, stream>>>(qkv_w, Wqkv, 3*CH*CH);
  k_cast<<<dim3((CH*CH)/256),   256, 0, stream>>>(proj_w, Wproj, CH*CH);

  k_gemm<0><<<dim3(MPAD/64, (3*CH)/64), 256, 0, stream>>>(Xbf, Wqkv, qkv_b, Qb, Kb, Vb, nullptr);
  k_transpose_v<<<dim3(64, NPAD/64), 256, 0, stream>>>(Vb, Vt);
  k_attn<<<dim3(64, NPAD/64), 256, 0, stream>>>(Qb, Kb, Vt, AttO);
  k_gemm<1><<<dim3(MPAD/64, CH/64), 256, 0, stream>>>(AttO, Wproj, proj_b, nullptr, nullptr, nullptr, out);
}

// Round 2
// 265.668 us; speedup vs baseline: 1.5475x; 1.5475x over previous
//
#include <hip/hip_runtime.h>
#include <hip/hip_bf16.h>

typedef short s16x8 __attribute__((ext_vector_type(8)));
typedef float f32x4 __attribute__((ext_vector_type(4)));
typedef float f32x16 __attribute__((ext_vector_type(16)));
typedef unsigned short u16;
typedef unsigned int   u32;
typedef u16 u16x4 __attribute__((ext_vector_type(4)));

#define SEQ  1370
#define CH   1024
#define NH   16
#define HD   64
#define BN   5480      // 4*1370
#define MPAD 5504      // 86*64
#define NPAD 1408      // 22*64
#define NQT  43        // ceil(1370/32)
#define NKT64 22       // NPAD/64

__device__ __forceinline__ u16 f2bf(float f){
  union { float f; unsigned u; } v; v.f = f;
  unsigned u = v.u;
  return (u16)((u + 0x7FFFu + ((u >> 16) & 1u)) >> 16);   // RNE
}

__device__ __forceinline__ u32 cvt_pk_bf16(float lo, float hi){
  u32 r;
  asm("v_cvt_pk_bf16_f32 %0, %1, %2" : "=v"(r) : "v"(lo), "v"(hi));
  return r;
}

// ---- casts ----
__global__ __launch_bounds__(256) void k_cast_tokens(const float* __restrict__ in, u16* __restrict__ out){
  int i = blockIdx.x * 256 + threadIdx.x;
  if(i >= MPAD*CH) return;
  int row = i >> 10;
  out[i] = (row < BN) ? f2bf(in[i]) : (u16)0;   // zero-pad M tail
}

__global__ __launch_bounds__(256) void k_cast(const float* __restrict__ in, u16* __restrict__ out, int n){
  int i = blockIdx.x * 256 + threadIdx.x;
  if(i < n) out[i] = f2bf(in[i]);
}

// ---- NT GEMM: C[m][n] = sum_k A[m][k]*B[n][k] (+bias), 64x64 tile, 4 waves ----
template<int MODE>
__global__ __launch_bounds__(256) void k_gemm(
    const u16* __restrict__ A, const u16* __restrict__ Bw, const float* __restrict__ bias,
    u16* __restrict__ q, u16* __restrict__ kk, u16* __restrict__ vv, float* __restrict__ out)
{
  __shared__ u16 As[64][40];
  __shared__ u16 Bs[64][40];
  const int m0 = blockIdx.x * 64;
  const int n0 = blockIdx.y * 64;
  const int t = threadIdx.x;
  const int lane = t & 63;
  const int w = t >> 6;
  const int wm = w >> 1, wn = w & 1;
  const int g = lane >> 4, lr = lane & 15;
  const int ldrow = t >> 2, ldc = (t & 3) * 8;

  f32x4 z = {0.f,0.f,0.f,0.f};
  f32x4 acc[2][2] = {{z,z},{z,z}};

  for(int k0 = 0; k0 < 1024; k0 += 32){
    s16x8 av = *reinterpret_cast<const s16x8*>(A  + (size_t)(m0 + ldrow) * 1024 + k0 + ldc);
    s16x8 bv = *reinterpret_cast<const s16x8*>(Bw + (size_t)(n0 + ldrow) * 1024 + k0 + ldc);
    __syncthreads();
    *reinterpret_cast<s16x8*>(&As[ldrow][ldc]) = av;
    *reinterpret_cast<s16x8*>(&Bs[ldrow][ldc]) = bv;
    __syncthreads();
    s16x8 af0 = *reinterpret_cast<const s16x8*>(&As[wm*32      + lr][g*8]);
    s16x8 af1 = *reinterpret_cast<const s16x8*>(&As[wm*32 + 16 + lr][g*8]);
    s16x8 bf0 = *reinterpret_cast<const s16x8*>(&Bs[wn*32      + lr][g*8]);
    s16x8 bf1 = *reinterpret_cast<const s16x8*>(&Bs[wn*32 + 16 + lr][g*8]);
    acc[0][0] = __builtin_amdgcn_mfma_f32_16x16x32_bf16(af0, bf0, acc[0][0], 0,0,0);
    acc[0][1] = __builtin_amdgcn_mfma_f32_16x16x32_bf16(af0, bf1, acc[0][1], 0,0,0);
    acc[1][0] = __builtin_amdgcn_mfma_f32_16x16x32_bf16(af1, bf0, acc[1][0], 0,0,0);
    acc[1][1] = __builtin_amdgcn_mfma_f32_16x16x32_bf16(af1, bf1, acc[1][1], 0,0,0);
  }

  for(int mi = 0; mi < 2; mi++){
    for(int ni = 0; ni < 2; ni++){
      int col = n0 + wn*32 + ni*16 + lr;
      float bb = bias[col];
      for(int r = 0; r < 4; r++){
        int row = m0 + wm*32 + mi*16 + g*4 + r;
        if(row >= BN) continue;
        float v = acc[mi][ni][r] + bb;
        if constexpr (MODE == 0){
          int b = row / SEQ, n = row - b*SEQ;
          int tt = col >> 10, h = (col >> 6) & 15, cc = col & 63;
          size_t bh = (size_t)(b*NH + h);
          if(tt == 0)      q [(bh*NPAD + n)*HD + cc] = f2bf(v * 0.125f);  // fold scale (pow2: exact)
          else if(tt == 1) kk[(bh*NPAD + n)*HD + cc] = f2bf(v);
          else             vv[(bh*NPAD + n)*HD + cc] = f2bf(v);
        } else {
          out[(size_t)row * CH + col] = v;
        }
      }
    }
  }
}

// ---- V[bh][n][cc] -> Vt[bh][cc][n], zero-fills n in [SEQ,NPAD) ----
__global__ __launch_bounds__(256) void k_transpose_v(const u16* __restrict__ V, u16* __restrict__ Vt){
  __shared__ u16 Ts[64][80];
  const int bh = blockIdx.x, nt = blockIdx.y;
  const int n0 = nt * 64;
  const int t = threadIdx.x;
  const int row = t >> 3;
  const int c8  = (t & 7) * 8;
  const u16* vb = V + (size_t)bh * NPAD * HD;
  for(int i = 0; i < 2; i++){
    int r = row + i*32;
    int n = n0 + r;
    s16x8 val = {0,0,0,0,0,0,0,0};
    if(n < SEQ) val = *reinterpret_cast<const s16x8*>(vb + (size_t)n*HD + c8);
    *reinterpret_cast<s16x8*>(&Ts[r][c8]) = val;
  }
  __syncthreads();
  u16* vtb = Vt + (size_t)bh * HD * NPAD;
  for(int i = 0; i < 2; i++){
    int cc = row + i*32;
    s16x8 o;
    for(int j = 0; j < 8; j++) o[j] = Ts[c8 + j][cc];
    *reinterpret_cast<s16x8*>(vtb + (size_t)cc*NPAD + n0 + c8) = o;
  }
}

// ---- flash attention, swapped-QK 32x32 structure, 1 wave = 32 q rows ----
// No LDS, no barriers. Softmax fully in-register (T12: cvt_pk + permlane32_swap).
__global__ __launch_bounds__(64,3) void k_attn2(
    const u16* __restrict__ Q, const u16* __restrict__ K,
    const u16* __restrict__ Vt, u16* __restrict__ O)
{
  const int qt = blockIdx.x;          // 0..42 (fast dim: consecutive blocks share bh)
  const int bh = blockIdx.y;          // 0..63
  const int lane = threadIdx.x;
  const int col = lane & 31;          // q column (QK) / d row (PV A) / k row (QK A)
  const int hi  = lane >> 5;
  const int n0  = qt * 32;

  const u16* qb = Q  + (size_t)bh * NPAD * HD;
  const u16* kb = K  + (size_t)bh * NPAD * HD;
  const u16* vb = Vt + (size_t)bh * HD * NPAD;

  // Q fragments: B-operand for QK (lane col = q row, d contiguous)
  s16x8 qf[4];
  #pragma unroll
  for(int dt=0; dt<4; dt++)
    qf[dt] = *reinterpret_cast<const s16x8*>(qb + (size_t)(n0+col)*HD + dt*16 + hi*8);

  f32x16 accO[2];          // O^T[d][q]: dt in {0,1} covers d 0..31 / 32..63
  #pragma unroll
  for(int i=0;i<16;i++){ accO[0][i]=0.f; accO[1][i]=0.f; }
  float m_run = -1e30f, l_run = 0.f;

  for(int kt=0; kt<NKT64; kt++){
    const int kj0 = kt*64;
    // ---- QK^T (swapped): St[s] = K_sub * Q^T -> S^T[k][q] ----
    f32x16 St[2];
    #pragma unroll
    for(int s=0;s<2;s++){
      #pragma unroll
      for(int i=0;i<16;i++) St[s][i]=0.f;
      const u16* krow = kb + (size_t)(kj0 + s*32 + col)*HD + hi*8;
      #pragma unroll
      for(int dt=0;dt<4;dt++){
        s16x8 kf = *reinterpret_cast<const s16x8*>(krow + dt*16);
        St[s] = __builtin_amdgcn_mfma_f32_32x32x16_bf16(kf, qf[dt], St[s], 0,0,0);
      }
    }
    // ---- mask (wave-uniform branch: only tail tiles pay) ----
    float p[32];
    if(kj0 + 64 <= SEQ){
      #pragma unroll
      for(int s=0;s<2;s++)
        #pragma unroll
        for(int r=0;r<16;r++) p[s*16+r] = St[s][r];
    } else {
      #pragma unroll
      for(int s=0;s<2;s++)
        #pragma unroll
        for(int r=0;r<16;r++){
          int k = kj0 + s*32 + (r&3) + 8*(r>>2) + 4*hi;
          p[s*16+r] = (k < SEQ) ? St[s][r] : -1e30f;
        }
    }
    // ---- online softmax: in-lane tree + one cross-half exchange ----
    float red[16];
    #pragma unroll
    for(int i=0;i<16;i++) red[i] = fmaxf(p[i], p[i+16]);
    #pragma unroll
    for(int s2=8;s2>=1;s2>>=1)
      #pragma unroll
      for(int i=0;i<8;i++) if(i<s2) red[i] = fmaxf(red[i], red[i+s2]);
    float mx = fmaxf(red[0], __shfl_xor(red[0], 32));
    float mnew = fmaxf(m_run, mx);
    float alpha = __expf(m_run - mnew);
    m_run = mnew;
    #pragma unroll
    for(int i=0;i<32;i++) p[i] = __expf(p[i] - mnew);
    float sr[16];
    #pragma unroll
    for(int i=0;i<16;i++) sr[i] = p[i] + p[i+16];
    #pragma unroll
    for(int s2=8;s2>=1;s2>>=1)
      #pragma unroll
      for(int i=0;i<8;i++) if(i<s2) sr[i] += sr[i+s2];
    float sum = sr[0] + __shfl_xor(sr[0], 32);
    l_run = l_run * alpha + sum;
    #pragma unroll
    for(int i=0;i<16;i++){ accO[0][i]*=alpha; accO[1][i]*=alpha; }
    // ---- P repack to PV B-frags: cvt_pk pairs + permlane32_swap (T12) ----
    union PF { u32 w[4]; s16x8 v; };
    PF pf[4];   // kh = 0..3 : k_local 16-chunks
    #pragma unroll
    for(int s=0;s<2;s++){
      #pragma unroll
      for(int hh=0; hh<2; hh++){
        const int b0 = s*16 + hh*8;
        u32 w0 = cvt_pk_bf16(p[b0+0], p[b0+1]);
        u32 w1 = cvt_pk_bf16(p[b0+2], p[b0+3]);
        u32 w2 = cvt_pk_bf16(p[b0+4], p[b0+5]);
        u32 w3 = cvt_pk_bf16(p[b0+6], p[b0+7]);
        auto r02 = __builtin_amdgcn_permlane32_swap(w0, w2, false, false);
        auto r13 = __builtin_amdgcn_permlane32_swap(w1, w3, false, false);
        pf[s*2+hh].w[0] = r02[0];
        pf[s*2+hh].w[1] = r13[0];
        pf[s*2+hh].w[2] = r02[1];
        pf[s*2+hh].w[3] = r13[1];
      }
    }
    // ---- PV: accO[dt] += V^T * P^T ----
    #pragma unroll
    for(int kh=0; kh<4; kh++){
      const u16* vrow = vb + (size_t)col*NPAD + kj0 + kh*16 + hi*8;
      #pragma unroll
      for(int dt=0; dt<2; dt++){
        s16x8 vf = *reinterpret_cast<const s16x8*>(vrow + (size_t)dt*32*NPAD);
        accO[dt] = __builtin_amdgcn_mfma_f32_32x32x16_bf16(vf, pf[kh].v, accO[dt], 0,0,0);
      }
    }
  }

  // ---- epilogue: O^T regs -> O[b*SEQ+n][h*64+d], packed 4-bf16 stores ----
  const int n = n0 + col;
  if(n < SEQ){
    float inv = 1.0f / l_run;
    const int b = bh >> 4, h = bh & 15;
    u16* orow = O + ((size_t)(b*SEQ + n))*CH + h*HD;
    #pragma unroll
    for(int dt=0; dt<2; dt++)
      #pragma unroll
      for(int qd=0; qd<4; qd++){
        u16x4 ov;
        #pragma unroll
        for(int j=0;j<4;j++) ov[j] = f2bf(accO[dt][qd*4+j]*inv);
        *reinterpret_cast<u16x4*>(orow + dt*32 + qd*8 + hi*4) = ov;
      }
  }
}

extern "C" void kernel_launch(void* const* d_in, const int* in_sizes, int n_in,
                              void* d_out, int out_size, void* d_ws, size_t ws_size,
                              hipStream_t stream)
{
  const float* tokens = (const float*)d_in[0];
  const float* qkv_w  = (const float*)d_in[1];
  const float* qkv_b  = (const float*)d_in[2];
  const float* proj_w = (const float*)d_in[3];
  const float* proj_b = (const float*)d_in[4];
  float* out = (float*)d_out;

  char* ws = (char*)d_ws;
  u16* Xbf   = (u16*)(ws);              // MPAD*1024*2        = 11,272,192 B
  u16* Wqkv  = (u16*)(ws + 11272192);   // 3072*1024*2        =  6,291,456
  u16* Wproj = (u16*)(ws + 17563648);   // 1024*1024*2        =  2,097,152
  u16* Qb    = (u16*)(ws + 19660800);   // 64*1408*64*2       = 11,534,336
  u16* Kb    = (u16*)(ws + 31195136);
  u16* Vb    = (u16*)(ws + 42729472);
  u16* Vt    = (u16*)(ws + 54263808);
  u16* AttO  = (u16*)(ws + 65798144);   // MPAD*1024*2 ; end ~77 MB

  k_cast_tokens<<<dim3((MPAD*CH)/256), 256, 0, stream>>>(tokens, Xbf);
  k_cast<<<dim3((3*CH*CH)/256), 256, 0, stream>>>(qkv_w, Wqkv, 3*CH*CH);
  k_cast<<<dim3((CH*CH)/256),   256, 0, stream>>>(proj_w, Wproj, CH*CH);

  k_gemm<0><<<dim3(MPAD/64, (3*CH)/64), 256, 0, stream>>>(Xbf, Wqkv, qkv_b, Qb, Kb, Vb, nullptr);
  k_transpose_v<<<dim3(64, NPAD/64), 256, 0, stream>>>(Vb, Vt);
  k_attn2<<<dim3(NQT, 64), 64, 0, stream>>>(Qb, Kb, Vt, AttO);
  k_gemm<1><<<dim3(MPAD/64, CH/64), 256, 0, stream>>>(AttO, Wproj, proj_b, nullptr, nullptr, nullptr, out);
}

// Round 3
// 253.471 us; speedup vs baseline: 1.6220x; 1.0481x over previous
//
#include <hip/hip_runtime.h>
#include <hip/hip_bf16.h>

typedef short s16x8 __attribute__((ext_vector_type(8)));
typedef float f32x4 __attribute__((ext_vector_type(4)));
typedef float f32x16 __attribute__((ext_vector_type(16)));
typedef unsigned short u16;
typedef unsigned int   u32;
typedef u16 u16x4 __attribute__((ext_vector_type(4)));

#define SEQ  1370
#define CH   1024
#define NH   16
#define HD   64
#define BN   5480      // 4*1370
#define MPAD 5504      // 43*128
#define NPAD 1408      // 22*64
#define NQT  43        // ceil(1370/32)
#define NKT64 22       // NPAD/64

// log2(e) folded into q scale: exp(x) = exp2(x*log2e)
#define QSCALE 0.18033688f   // 0.125 * 1.44269504089

__device__ __forceinline__ u16 f2bf(float f){
  union { float f; unsigned u; } v; v.f = f;
  unsigned u = v.u;
  return (u16)((u + 0x7FFFu + ((u >> 16) & 1u)) >> 16);   // RNE
}

__device__ __forceinline__ u32 cvt_pk_bf16(float lo, float hi){
  u32 r;
  asm("v_cvt_pk_bf16_f32 %0, %1, %2" : "=v"(r) : "v"(lo), "v"(hi));
  return r;
}

#define GLOAD16(gp, lp) __builtin_amdgcn_global_load_lds( \
    (const __attribute__((address_space(1))) void*)(gp), \
    (__attribute__((address_space(3))) void*)(lp), 16, 0, 0)

// ---- casts ----
__global__ __launch_bounds__(256) void k_cast_tokens(const float* __restrict__ in, u16* __restrict__ out){
  int i = blockIdx.x * 256 + threadIdx.x;
  if(i >= MPAD*CH) return;
  int row = i >> 10;
  out[i] = (row < BN) ? f2bf(in[i]) : (u16)0;   // zero-pad M tail
}

__global__ __launch_bounds__(256) void k_cast(const float* __restrict__ in, u16* __restrict__ out, int n){
  int i = blockIdx.x * 256 + threadIdx.x;
  if(i < n) out[i] = f2bf(in[i]);
}

// ---- m97-structure NT GEMM: 128x128 tile, BK=32, global_load_lds, 4 waves ----
// C[m][n] = sum_k A[m][k]*B[n][k] + bias[n]
// MODE 0: QKV epilogue (scatter q*QSCALE / k / v into [bh][NPAD][64] bf16)
// MODE 1: proj epilogue (fp32 out + bias)
template<int MODE>
__global__ __launch_bounds__(256,2) void k_gemm128(
    const u16* __restrict__ A, const u16* __restrict__ Bw, const float* __restrict__ bias,
    u16* __restrict__ q, u16* __restrict__ kk, u16* __restrict__ vv, float* __restrict__ out)
{
  __shared__ u16 As[128*32];   // linear [row][32] — global_load_lds needs linear dest
  __shared__ u16 Bs[128*32];
  const int t = threadIdx.x;
  const int lane = t & 63;
  const int w = t >> 6;
  const int wm = w >> 1, wn = w & 1;          // 2x2 wave grid, 64x64 per wave
  const int g = lane >> 4, lr = lane & 15;
  const int m0 = blockIdx.x * 128, n0 = blockIdx.y * 128;

  // per-lane global src for global_load_lds (lane i of wave w covers LDS elems w*512+i*8)
  const u16* ga0 = A  + (size_t)(m0 + (t >> 2)) * 1024 + (t & 3) * 8;
  const u16* gb0 = Bw + (size_t)(n0 + (t >> 2)) * 1024 + (t & 3) * 8;
  u16* law = As + w * 512;
  u16* lbw = Bs + w * 512;

  f32x4 z = {0.f,0.f,0.f,0.f};
  f32x4 acc[4][4] = {{z,z,z,z},{z,z,z,z},{z,z,z,z},{z,z,z,z}};

  for(int k0 = 0; k0 < 1024; k0 += 32){
    GLOAD16(ga0 + k0,             law);
    GLOAD16(ga0 + k0 + 64*1024,   law + 2048);
    GLOAD16(gb0 + k0,             lbw);
    GLOAD16(gb0 + k0 + 64*1024,   lbw + 2048);
    __syncthreads();              // vmcnt(0) drain + barrier: tiles resident
    s16x8 af[4], bf[4];
#pragma unroll
    for(int mf = 0; mf < 4; mf++)
      af[mf] = *reinterpret_cast<const s16x8*>(&As[(wm*64 + mf*16 + lr)*32 + g*8]);
#pragma unroll
    for(int nf = 0; nf < 4; nf++)
      bf[nf] = *reinterpret_cast<const s16x8*>(&Bs[(wn*64 + nf*16 + lr)*32 + g*8]);
#pragma unroll
    for(int mf = 0; mf < 4; mf++)
#pragma unroll
      for(int nf = 0; nf < 4; nf++)
        acc[mf][nf] = __builtin_amdgcn_mfma_f32_16x16x32_bf16(af[mf], bf[nf], acc[mf][nf], 0,0,0);
    __syncthreads();              // all reads done before next overwrite
  }

#pragma unroll
  for(int mf = 0; mf < 4; mf++){
#pragma unroll
    for(int nf = 0; nf < 4; nf++){
      int colc = n0 + wn*64 + nf*16 + lr;
      float bb = bias[colc];
#pragma unroll
      for(int r = 0; r < 4; r++){
        int row = m0 + wm*64 + mf*16 + g*4 + r;   // C/D: col=lane&15, row=(lane>>4)*4+reg
        if(row >= BN) continue;
        float v = acc[mf][nf][r] + bb;
        if constexpr (MODE == 0){
          int b = row / SEQ, n = row - b*SEQ;
          int tt = colc >> 10, h = (colc >> 6) & 15, cc = colc & 63;
          size_t bh = (size_t)(b*NH + h);
          if(tt == 0)      q [(bh*NPAD + n)*HD + cc] = f2bf(v * QSCALE);
          else if(tt == 1) kk[(bh*NPAD + n)*HD + cc] = f2bf(v);
          else             vv[(bh*NPAD + n)*HD + cc] = f2bf(v);
        } else {
          out[(size_t)row * CH + colc] = v;
        }
      }
    }
  }
}

// ---- V[bh][n][cc] -> Vt[bh][cc][n], zero-fills n in [SEQ,NPAD) ----
__global__ __launch_bounds__(256) void k_transpose_v(const u16* __restrict__ V, u16* __restrict__ Vt){
  __shared__ u16 Ts[64][80];
  const int bh = blockIdx.x, nt = blockIdx.y;
  const int n0 = nt * 64;
  const int t = threadIdx.x;
  const int row = t >> 3;
  const int c8  = (t & 7) * 8;
  const u16* vb = V + (size_t)bh * NPAD * HD;
  for(int i = 0; i < 2; i++){
    int r = row + i*32;
    int n = n0 + r;
    s16x8 val = {0,0,0,0,0,0,0,0};
    if(n < SEQ) val = *reinterpret_cast<const s16x8*>(vb + (size_t)n*HD + c8);
    *reinterpret_cast<s16x8*>(&Ts[r][c8]) = val;
  }
  __syncthreads();
  u16* vtb = Vt + (size_t)bh * HD * NPAD;
  for(int i = 0; i < 2; i++){
    int cc = row + i*32;
    s16x8 o;
    for(int j = 0; j < 8; j++) o[j] = Ts[c8 + j][cc];
    *reinterpret_cast<s16x8*>(vtb + (size_t)cc*NPAD + n0 + c8) = o;
  }
}

// ---- flash attention v3: swapped-QK 32x32, K-prefetch + early-V, exp2, defer-max ----
__global__ __launch_bounds__(64,2) void k_attn3(
    const u16* __restrict__ Q, const u16* __restrict__ K,
    const u16* __restrict__ Vt, u16* __restrict__ O)
{
  const int qt = blockIdx.x;
  const int bh = blockIdx.y;
  const int lane = threadIdx.x;
  const int col = lane & 31;
  const int hi  = lane >> 5;
  const int n0  = qt * 32;

  const u16* qb = Q  + (size_t)bh * NPAD * HD;
  const u16* kb = K  + (size_t)bh * NPAD * HD;
  const u16* vb = Vt + (size_t)bh * HD * NPAD;

  s16x8 qf[4];
#pragma unroll
  for(int dt=0; dt<4; dt++)
    qf[dt] = *reinterpret_cast<const s16x8*>(qb + (size_t)(n0+col)*HD + dt*16 + hi*8);

  f32x16 accO[2];
#pragma unroll
  for(int i=0;i<16;i++){ accO[0][i]=0.f; accO[1][i]=0.f; }
  float m_run = -1e30f, l_run = 0.f;

  s16x8 kfA[8], kfB[8], vf[8];

#define LOADK(dst, KJ) { \
  const u16* kr0_ = kb + (size_t)((KJ) + col)*HD + hi*8;      \
  const u16* kr1_ = kb + (size_t)((KJ) + 32 + col)*HD + hi*8; \
  _Pragma("unroll") \
  for(int dt_=0; dt_<4; dt_++){ \
    dst[dt_]   = *reinterpret_cast<const s16x8*>(kr0_ + dt_*16); \
    dst[4+dt_] = *reinterpret_cast<const s16x8*>(kr1_ + dt_*16); } }

#define LOADV(dst, KJ) { \
  const u16* vr0_ = vb + (size_t)col*NPAD + (KJ) + hi*8; \
  const u16* vr1_ = vr0_ + (size_t)32*NPAD; \
  _Pragma("unroll") \
  for(int kh_=0; kh_<4; kh_++){ \
    dst[kh_]   = *reinterpret_cast<const s16x8*>(vr0_ + kh_*16); \
    dst[4+kh_] = *reinterpret_cast<const s16x8*>(vr1_ + kh_*16); } }

#define PROCESS(KJ, KF, VF) { \
  f32x16 St[2]; \
  _Pragma("unroll") \
  for(int s_=0;s_<2;s_++){ \
    _Pragma("unroll") for(int i_=0;i_<16;i_++) St[s_][i_]=0.f; \
    _Pragma("unroll") \
    for(int dt_=0;dt_<4;dt_++) \
      St[s_] = __builtin_amdgcn_mfma_f32_32x32x16_bf16(KF[s_*4+dt_], qf[dt_], St[s_], 0,0,0); \
  } \
  float p[32]; \
  if((KJ) + 64 <= SEQ){ \
    _Pragma("unroll") for(int i_=0;i_<32;i_++) p[i_] = St[i_>>4][i_&15]; \
  } else { \
    _Pragma("unroll") \
    for(int s_=0;s_<2;s_++) \
      _Pragma("unroll") \
      for(int r_=0;r_<16;r_++){ \
        int k_ = (KJ) + s_*32 + (r_&3) + 8*(r_>>2) + 4*hi; \
        p[s_*16+r_] = (k_ < SEQ) ? St[s_][r_] : -1e30f; \
      } \
  } \
  float red[16]; \
  _Pragma("unroll") for(int i_=0;i_<16;i_++) red[i_] = fmaxf(p[i_], p[i_+16]); \
  _Pragma("unroll") \
  for(int s2_=8;s2_>=1;s2_>>=1) \
    _Pragma("unroll") for(int i_=0;i_<8;i_++) if(i_<s2_) red[i_] = fmaxf(red[i_], red[i_+s2_]); \
  float mx = fmaxf(red[0], __shfl_xor(red[0], 32)); \
  if(!__all(mx <= m_run + 8.f)){   /* defer-max (T13): rescale only on real growth */ \
    float mnew = fmaxf(m_run, mx); \
    float alpha = exp2f(m_run - mnew); \
    m_run = mnew; \
    l_run *= alpha; \
    _Pragma("unroll") for(int i_=0;i_<16;i_++){ accO[0][i_]*=alpha; accO[1][i_]*=alpha; } \
  } \
  _Pragma("unroll") for(int i_=0;i_<32;i_++) p[i_] = exp2f(p[i_] - m_run); \
  float sr[16]; \
  _Pragma("unroll") for(int i_=0;i_<16;i_++) sr[i_] = p[i_] + p[i_+16]; \
  _Pragma("unroll") \
  for(int s2_=8;s2_>=1;s2_>>=1) \
    _Pragma("unroll") for(int i_=0;i_<8;i_++) if(i_<s2_) sr[i_] += sr[i_+s2_]; \
  l_run += sr[0] + __shfl_xor(sr[0], 32); \
  union PF { u32 w[4]; s16x8 v; } pf[4]; \
  _Pragma("unroll") \
  for(int s_=0;s_<2;s_++){ \
    _Pragma("unroll") \
    for(int hh_=0; hh_<2; hh_++){ \
      const int b0_ = s_*16 + hh_*8; \
      u32 w0_ = cvt_pk_bf16(p[b0_+0], p[b0_+1]); \
      u32 w1_ = cvt_pk_bf16(p[b0_+2], p[b0_+3]); \
      u32 w2_ = cvt_pk_bf16(p[b0_+4], p[b0_+5]); \
      u32 w3_ = cvt_pk_bf16(p[b0_+6], p[b0_+7]); \
      auto r02_ = __builtin_amdgcn_permlane32_swap(w0_, w2_, false, false); \
      auto r13_ = __builtin_amdgcn_permlane32_swap(w1_, w3_, false, false); \
      pf[s_*2+hh_].w[0] = r02_[0]; \
      pf[s_*2+hh_].w[1] = r13_[0]; \
      pf[s_*2+hh_].w[2] = r02_[1]; \
      pf[s_*2+hh_].w[3] = r13_[1]; \
    } \
  } \
  _Pragma("unroll") \
  for(int dt_=0; dt_<2; dt_++) \
    _Pragma("unroll") \
    for(int kh_=0; kh_<4; kh_++) \
      accO[dt_] = __builtin_amdgcn_mfma_f32_32x32x16_bf16(VF[dt_*4+kh_], pf[kh_].v, accO[dt_], 0,0,0); \
}

  LOADK(kfA, 0);
  for(int kt = 0; kt < NKT64; kt += 2){
    const int kj0 = kt * 64;
    LOADV(vf, kj0);                         // V for this tile: used ~after softmax
    LOADK(kfB, kj0 + 64);                   // K prefetch: used next half
    PROCESS(kj0, kfA, vf);
    LOADV(vf, kj0 + 64);
    if(kt + 2 < NKT64) LOADK(kfA, kj0 + 128);
    PROCESS(kj0 + 64, kfB, vf);
  }

  // ---- epilogue ----
  const int n = n0 + col;
  if(n < SEQ){
    float inv = 1.0f / l_run;
    const int b = bh >> 4, h = bh & 15;
    u16* orow = O + ((size_t)(b*SEQ + n))*CH + h*HD;
#pragma unroll
    for(int dt=0; dt<2; dt++)
#pragma unroll
      for(int qd=0; qd<4; qd++){
        u16x4 ov;
#pragma unroll
        for(int j=0;j<4;j++) ov[j] = f2bf(accO[dt][qd*4+j]*inv);
        *reinterpret_cast<u16x4*>(orow + dt*32 + qd*8 + hi*4) = ov;
      }
  }
}

extern "C" void kernel_launch(void* const* d_in, const int* in_sizes, int n_in,
                              void* d_out, int out_size, void* d_ws, size_t ws_size,
                              hipStream_t stream)
{
  const float* tokens = (const float*)d_in[0];
  const float* qkv_w  = (const float*)d_in[1];
  const float* qkv_b  = (const float*)d_in[2];
  const float* proj_w = (const float*)d_in[3];
  const float* proj_b = (const float*)d_in[4];
  float* out = (float*)d_out;

  char* ws = (char*)d_ws;
  u16* Xbf   = (u16*)(ws);              // MPAD*1024*2        = 11,272,192 B
  u16* Wqkv  = (u16*)(ws + 11272192);   // 3072*1024*2        =  6,291,456
  u16* Wproj = (u16*)(ws + 17563648);   // 1024*1024*2        =  2,097,152
  u16* Qb    = (u16*)(ws + 19660800);   // 64*1408*64*2       = 11,534,336
  u16* Kb    = (u16*)(ws + 31195136);
  u16* Vb    = (u16*)(ws + 42729472);
  u16* Vt    = (u16*)(ws + 54263808);
  u16* AttO  = (u16*)(ws + 65798144);   // MPAD*1024*2 ; end ~77 MB

  k_cast_tokens<<<dim3((MPAD*CH)/256), 256, 0, stream>>>(tokens, Xbf);
  k_cast<<<dim3((3*CH*CH)/256), 256, 0, stream>>>(qkv_w, Wqkv, 3*CH*CH);
  k_cast<<<dim3((CH*CH)/256),   256, 0, stream>>>(proj_w, Wproj, CH*CH);

  k_gemm128<0><<<dim3(MPAD/128, (3*CH)/128), 256, 0, stream>>>(Xbf, Wqkv, qkv_b, Qb, Kb, Vb, nullptr);
  k_transpose_v<<<dim3(64, NPAD/64), 256, 0, stream>>>(Vb, Vt);
  k_attn3<<<dim3(NQT, 64), 64, 0, stream>>>(Qb, Kb, Vt, AttO);
  k_gemm128<1><<<dim3(MPAD/128, CH/128), 256, 0, stream>>>(AttO, Wproj, proj_b, nullptr, nullptr, nullptr, out);
}